// Round 3
// baseline (495.100 us; speedup 1.0000x reference)
//
#include <hip/hip_runtime.h>

// PairDistanceLoss: loss_i = (sum_{y=1} exp(x)) * (sum_{y=0} exp(-x)) / (ni*(C-ni))
// output = mean_i loss_i (fp32 scalar). N=16384 rows, C=4096 cols.
//
// R2 experiment: OCCUPANCY. Revert y to NT (R1 cacheable-y regressed 136->165us;
// cache-policy axis now closed: NT-both is best). Slim the register pipeline to
// 2-deep x 4 dwordx4 (32 buffer VGPRs, was 64) and force __launch_bounds__(256,8)
// -> 8 waves/SIMD (was ~4). Per-wave in-flight halves (8KB) but waves double;
// total outstanding/CU unchanged and >>Little's-law need.
// Prediction: if occupancy limited read BW, pdl_rows 136->~105us (harness ~430);
// if neutral, all structure axes (depth/cache/occupancy) plateau at ~3.9 TB/s
// -> fixed per-CU read-tracking ceiling -> declare roofline.

typedef float v4f __attribute__((ext_vector_type(4)));
typedef int   v4i __attribute__((ext_vector_type(4)));

#define C_DIM 4096
#define BLOCK 256
#define NBLK  2048
#define WPB   (BLOCK / 64)       // 4 waves per block
#define RPW   2                  // rows per wave: 16384 / (2048*4)
// per chunk: 8 elements/lane = 2 dwordx4 x + 2 dwordx4 y; 8 chunks per row
#define CHUNKS (RPW * 8)         // 16 chunks per wave

__global__ __launch_bounds__(BLOCK, 8) void pdl_rows(const float* __restrict__ x,
                                                     const int* __restrict__ y,
                                                     float* __restrict__ partial) {
    const int lane  = threadIdx.x & 63;
    const int wave  = threadIdx.x >> 6;
    const int gwave = blockIdx.x * WPB + wave;
    const int rbase = gwave * RPW;

    float pos = 0.0f, neg = 0.0f;
    int cnt = 0;
    float wacc = 0.0f;  // lane-0 row results

    v4f xbuf[2][2];
    v4i ybuf[2][2];

    // chunk c in [0, 16): row = rbase + c/8, intra-row chunk c&7 (2 KB per chunk)
    auto prefetch = [&](int slot, int c) {
        const size_t rowoff = (size_t)(rbase + (c >> 3)) * C_DIM;
        const v4f* __restrict__ x4 = (const v4f*)(x + rowoff);
        const v4i* __restrict__ y4 = (const v4i*)(y + rowoff);
#pragma unroll
        for (int u = 0; u < 2; ++u) {
            const int i = lane + ((c & 7) * 2 + u) * 64;
            xbuf[slot][u] = __builtin_nontemporal_load(x4 + i);
            ybuf[slot][u] = __builtin_nontemporal_load(y4 + i);
        }
    };
    auto compute = [&](int slot) {
#pragma unroll
        for (int u = 0; u < 2; ++u) {
#pragma unroll
            for (int e = 0; e < 4; ++e) {
                const int   yy = ybuf[slot][u][e];
                const float xx = xbuf[slot][u][e];
                const float ex = __expf(yy ? xx : -xx);
                pos += yy ? ex : 0.0f;
                neg += yy ? 0.0f : ex;
                cnt += yy;
            }
        }
    };
    auto finish_row = [&]() {
#pragma unroll
        for (int off = 32; off >= 1; off >>= 1) {
            pos += __shfl_down(pos, off, 64);
            neg += __shfl_down(neg, off, 64);
            cnt += __shfl_down(cnt, off, 64);
        }
        if (lane == 0) {
            const float denom = (float)cnt * (float)(C_DIM - cnt);
            wacc += (pos * neg) / denom;
        }
        pos = 0.0f; neg = 0.0f; cnt = 0;
    };

    // 2-deep pipeline, fully unrolled so buffer indices are compile-time (rule #20)
    prefetch(0, 0);
    prefetch(1, 1);
#pragma unroll
    for (int c = 0; c < CHUNKS; ++c) {
        compute(c & 1);
        if (c + 2 < CHUNKS) prefetch(c & 1, c + 2);
        if (c == 7)          finish_row();  // row 0 done
        if (c == CHUNKS - 1) finish_row();  // row 1 done
    }

    __shared__ float sacc[WPB];
    if (lane == 0) sacc[wave] = wacc;
    __syncthreads();
    if (threadIdx.x == 0) {
        float b = 0.0f;
#pragma unroll
        for (int w = 0; w < WPB; ++w) b += sacc[w];
        partial[blockIdx.x] = b;
    }
}

__global__ __launch_bounds__(BLOCK) void pdl_reduce(const float* __restrict__ partial,
                                                    float* __restrict__ out,
                                                    int n_partial, float inv_n) {
    const float4* p4 = (const float4*)partial;
    float s = 0.0f;
    for (int i = threadIdx.x; i < n_partial / 4; i += BLOCK) {
        const float4 v = p4[i];
        s += (v.x + v.y) + (v.z + v.w);
    }
#pragma unroll
    for (int off = 32; off >= 1; off >>= 1) s += __shfl_down(s, off, 64);
    __shared__ float sw[BLOCK / 64];
    const int lane = threadIdx.x & 63;
    const int wave = threadIdx.x >> 6;
    if (lane == 0) sw[wave] = s;
    __syncthreads();
    if (threadIdx.x == 0) {
        float t = 0.0f;
#pragma unroll
        for (int w = 0; w < BLOCK / 64; ++w) t += sw[w];
        out[0] = t * inv_n;
    }
}

extern "C" void kernel_launch(void* const* d_in, const int* in_sizes, int n_in,
                              void* d_out, int out_size, void* d_ws, size_t ws_size,
                              hipStream_t stream) {
    const float* x = (const float*)d_in[0];
    const int*   y = (const int*)d_in[1];
    float* out = (float*)d_out;
    float* partial = (float*)d_ws;  // NBLK floats, fully rewritten each call

    const int n_rows = in_sizes[0] / C_DIM;  // 16384

    pdl_rows<<<NBLK, BLOCK, 0, stream>>>(x, y, partial);
    pdl_reduce<<<1, BLOCK, 0, stream>>>(partial, out, NBLK, 1.0f / (float)n_rows);
}

// Round 4
// 483.137 us; speedup vs baseline: 1.0248x; 1.0248x over previous
//
#include <hip/hip_runtime.h>

// PairDistanceLoss: loss_i = (sum_{y=1} exp(x)) * (sum_{y=0} exp(-x)) / (ni*(C-ni))
// output = mean_i loss_i (fp32 scalar). N=16384 rows, C=4096 cols.
//
// R3 experiment: STREAM TOPOLOGY. All prior variants interleave x[i]/y[i] reads
// per wave and all cap at ~3.8-3.9 TB/s read, while single-stream fill writes
// hit 6.7 TB/s. Split into two single-stream dispatches:
//   pdl_mask: y (256MB, NT, contiguous/wave) -> 1 bit/elem masks (8.4MB in ws)
//   pdl_x:    x (256MB, NT, contiguous/wave) + masks (u64/lane + shfl bcast)
// Traffic 512->528MB (+3%) but every stream is fill-like sequential.
// Prediction: win (~95us total, harness ~425) if dual-stream pairing was the
// cap; neutral (~137us) => structure-independent read ceiling => roofline.
// Fallback to verified 136us single-kernel if ws_size too small.

typedef float v4f __attribute__((ext_vector_type(4)));
typedef int   v4i __attribute__((ext_vector_type(4)));
typedef unsigned long long u64;

#define C_DIM 4096
#define BLOCK 256
#define NBLK  2048
#define WPB   (BLOCK / 64)        // 4 waves per block
#define RPW   2                   // rows per wave
#define GROUPS 16                 // dwordx4 instr-groups per row (4096/256)
#define WPR    64                 // u64 mask words per row (4096/64)

// ---------- phase 1: y -> bitmasks ----------
__global__ __launch_bounds__(BLOCK) void pdl_mask(const int* __restrict__ y,
                                                  u64* __restrict__ mask) {
    const int lane  = threadIdx.x & 63;
    const int wave  = threadIdx.x >> 6;
    const int gwave = blockIdx.x * WPB + wave;
    const int rbase = gwave * RPW;

#pragma unroll
    for (int r = 0; r < RPW; ++r) {
        const int row = rbase + r;
        const v4i* __restrict__ y4 = (const v4i*)(y + (size_t)row * C_DIM);
        u64* __restrict__ mrow = mask + (size_t)row * WPR;

        // 2-deep pipeline over 16 contiguous 1KB wave-loads
        v4i b0 = __builtin_nontemporal_load(y4 + lane);
        v4i b1 = __builtin_nontemporal_load(y4 + lane + 64);
#pragma unroll
        for (int k = 0; k < GROUPS; ++k) {
            const v4i v = (k & 1) ? b1 : b0;
            if (k + 2 < GROUPS) {
                if (k & 1) b1 = __builtin_nontemporal_load(y4 + lane + (k + 2) * 64);
                else       b0 = __builtin_nontemporal_load(y4 + lane + (k + 2) * 64);
            }
            const u64 w0 = __ballot(v[0] != 0);
            const u64 w1 = __ballot(v[1] != 0);
            const u64 w2 = __ballot(v[2] != 0);
            const u64 w3 = __ballot(v[3] != 0);
            // lanes 0-3 store the 4 words (each lane has all ballot results)
            const u64 w = (lane == 0) ? w0 : (lane == 1) ? w1 : (lane == 2) ? w2 : w3;
            if (lane < 4) mrow[k * 4 + lane] = w;
        }
    }
}

// ---------- phase 2: x + masks -> per-block partials ----------
__global__ __launch_bounds__(BLOCK) void pdl_x(const float* __restrict__ x,
                                               const u64* __restrict__ mask,
                                               float* __restrict__ partial) {
    const int lane  = threadIdx.x & 63;
    const int wave  = threadIdx.x >> 6;
    const int gwave = blockIdx.x * WPB + wave;
    const int rbase = gwave * RPW;

    float wacc = 0.0f;

#pragma unroll
    for (int r = 0; r < RPW; ++r) {
        const int row = rbase + r;
        const v4f* __restrict__ x4 = (const v4f*)(x + (size_t)row * C_DIM);

        // whole row's mask: one u64 per lane, coalesced 512B load (L2/L3-hot)
        const u64 myw = mask[(size_t)row * WPR + lane];

        float pos = 0.0f, neg = 0.0f;

        v4f b0 = __builtin_nontemporal_load(x4 + lane);
        v4f b1 = __builtin_nontemporal_load(x4 + lane + 64);
#pragma unroll
        for (int k = 0; k < GROUPS; ++k) {
            const v4f v = (k & 1) ? b1 : b0;
            if (k + 2 < GROUPS) {
                if (k & 1) b1 = __builtin_nontemporal_load(x4 + lane + (k + 2) * 64);
                else       b0 = __builtin_nontemporal_load(x4 + lane + (k + 2) * 64);
            }
#pragma unroll
            for (int e = 0; e < 4; ++e) {
                // word (k,e) lives in lane k*4+e; my element's bit is bit `lane`
                const u64 w = __shfl(myw, k * 4 + e, 64);
                const int bit = (int)((w >> lane) & 1ull);
                const float xx = v[e];
                const float ex = __expf(bit ? xx : -xx);
                pos += bit ? ex : 0.0f;
                neg += bit ? 0.0f : ex;
            }
        }

        int cnt = __popcll(myw);  // row count, distributed across lanes
#pragma unroll
        for (int off = 32; off >= 1; off >>= 1) {
            pos += __shfl_down(pos, off, 64);
            neg += __shfl_down(neg, off, 64);
            cnt += __shfl_down(cnt, off, 64);
        }
        if (lane == 0) {
            const float denom = (float)cnt * (float)(C_DIM - cnt);
            wacc += (pos * neg) / denom;
        }
    }

    __shared__ float sacc[WPB];
    if (lane == 0) sacc[wave] = wacc;
    __syncthreads();
    if (threadIdx.x == 0) {
        float b = 0.0f;
#pragma unroll
        for (int w = 0; w < WPB; ++w) b += sacc[w];
        partial[blockIdx.x] = b;
    }
}

// ---------- fallback: verified 136us single-kernel (R4-best) ----------
__global__ __launch_bounds__(BLOCK) void pdl_rows(const float* __restrict__ x,
                                                  const int* __restrict__ y,
                                                  float* __restrict__ partial) {
    const int lane  = threadIdx.x & 63;
    const int wave  = threadIdx.x >> 6;
    const int gwave = blockIdx.x * WPB + wave;
    const int rbase = gwave * RPW;

    float pos = 0.0f, neg = 0.0f;
    int cnt = 0;
    float wacc = 0.0f;

    v4f xa[4], xb[4];
    v4i ya[4], yb[4];

    auto prefetch = [&](v4f (&xv)[4], v4i (&yv)[4], int c) {
        const size_t rowoff = (size_t)(rbase + (c >> 2)) * C_DIM;
        const v4f* __restrict__ x4 = (const v4f*)(x + rowoff);
        const v4i* __restrict__ y4 = (const v4i*)(y + rowoff);
#pragma unroll
        for (int u = 0; u < 4; ++u) {
            const int i = lane + ((c & 3) * 4 + u) * 64;
            xv[u] = __builtin_nontemporal_load(x4 + i);
            yv[u] = __builtin_nontemporal_load(y4 + i);
        }
    };
    auto compute = [&](const v4f (&xv)[4], const v4i (&yv)[4]) {
#pragma unroll
        for (int u = 0; u < 4; ++u) {
#pragma unroll
            for (int e = 0; e < 4; ++e) {
                const int   yy = yv[u][e];
                const float xx = xv[u][e];
                const float ex = __expf(yy ? xx : -xx);
                pos += yy ? ex : 0.0f;
                neg += yy ? 0.0f : ex;
                cnt += yy;
            }
        }
    };
    auto finish_row = [&]() {
#pragma unroll
        for (int off = 32; off >= 1; off >>= 1) {
            pos += __shfl_down(pos, off, 64);
            neg += __shfl_down(neg, off, 64);
            cnt += __shfl_down(cnt, off, 64);
        }
        if (lane == 0) {
            const float denom = (float)cnt * (float)(C_DIM - cnt);
            wacc += (pos * neg) / denom;
        }
        pos = 0.0f; neg = 0.0f; cnt = 0;
    };

    prefetch(xa, ya, 0);
    prefetch(xb, yb, 1);
    compute(xa, ya);  prefetch(xa, ya, 2);
    compute(xb, yb);  prefetch(xb, yb, 3);
    compute(xa, ya);  prefetch(xa, ya, 4);
    compute(xb, yb);  prefetch(xb, yb, 5);
    finish_row();
    compute(xa, ya);  prefetch(xa, ya, 6);
    compute(xb, yb);  prefetch(xb, yb, 7);
    compute(xa, ya);
    compute(xb, yb);
    finish_row();

    __shared__ float sacc[WPB];
    if (lane == 0) sacc[wave] = wacc;
    __syncthreads();
    if (threadIdx.x == 0) {
        float b = 0.0f;
#pragma unroll
        for (int w = 0; w < WPB; ++w) b += sacc[w];
        partial[blockIdx.x] = b;
    }
}

__global__ __launch_bounds__(BLOCK) void pdl_reduce(const float* __restrict__ partial,
                                                    float* __restrict__ out,
                                                    int n_partial, float inv_n) {
    const float4* p4 = (const float4*)partial;
    float s = 0.0f;
    for (int i = threadIdx.x; i < n_partial / 4; i += BLOCK) {
        const float4 v = p4[i];
        s += (v.x + v.y) + (v.z + v.w);
    }
#pragma unroll
    for (int off = 32; off >= 1; off >>= 1) s += __shfl_down(s, off, 64);
    __shared__ float sw[BLOCK / 64];
    const int lane = threadIdx.x & 63;
    const int wave = threadIdx.x >> 6;
    if (lane == 0) sw[wave] = s;
    __syncthreads();
    if (threadIdx.x == 0) {
        float t = 0.0f;
#pragma unroll
        for (int w = 0; w < BLOCK / 64; ++w) t += sw[w];
        out[0] = t * inv_n;
    }
}

extern "C" void kernel_launch(void* const* d_in, const int* in_sizes, int n_in,
                              void* d_out, int out_size, void* d_ws, size_t ws_size,
                              hipStream_t stream) {
    const float* x = (const float*)d_in[0];
    const int*   y = (const int*)d_in[1];
    float* out = (float*)d_out;
    float* partial = (float*)d_ws;                      // NBLK floats (8 KB)
    u64*   mask    = (u64*)((char*)d_ws + 8192);        // 16384*64*8 = 8.39 MB

    const int n_rows = in_sizes[0] / C_DIM;             // 16384
    const size_t need = 8192 + (size_t)n_rows * WPR * sizeof(u64);

    if (ws_size >= need) {
        pdl_mask<<<NBLK, BLOCK, 0, stream>>>(y, mask);
        pdl_x<<<NBLK, BLOCK, 0, stream>>>(x, mask, partial);
    } else {
        pdl_rows<<<NBLK, BLOCK, 0, stream>>>(x, y, partial);
    }
    pdl_reduce<<<1, BLOCK, 0, stream>>>(partial, out, NBLK, 1.0f / (float)n_rows);
}

// Round 7
// 468.601 us; speedup vs baseline: 1.0565x; 1.0310x over previous
//
#include <hip/hip_runtime.h>

// PairDistanceLoss: loss_i = (sum_{y=1} exp(x)) * (sum_{y=0} exp(-x)) / (ni*(C-ni))
// output = mean_i loss_i (fp32 scalar). N=16384 rows, C=4096 cols.
//
// R4 experiment: DRAM STREAM COUNT. All prior variants (interleaved, split,
// hi-occ, cache policies) cap at 3.8-3.9 TB/s read while fills write at 6.7.
// Common factor: ~16k concurrent 1KB-granular read streams -> per-channel
// streams >> banks -> row activation per access. This version: 4 waves of a
// block COOPERATE on one row (wave w reads the w-th 4KB quarter; block access
// = one contiguous 16KB row), block sweeps 8 consecutive rows. Streams drop
// ~8x, bursts 16x longer. Same NT dwordx4 + 2-deep x 8-load pipeline.
// Per-row cross-wave reduce via 384B LDS, one sync at block end.
// Prediction: win (85-110us, harness ~410-435) if DRAM thrash was the cap;
// neutral (~136us) => all axes closed => read roofline ~3.9 TB/s.

typedef float v4f __attribute__((ext_vector_type(4)));
typedef int   v4i __attribute__((ext_vector_type(4)));

#define C_DIM 4096
#define BLOCK 256
#define NBLK  2048
#define WPB   (BLOCK / 64)   // 4 waves per block
#define RPB   8              // rows per block (16384 / 2048), one row per step

__global__ __launch_bounds__(BLOCK) void pdl_rows(const float* __restrict__ x,
                                                  const int* __restrict__ y,
                                                  float* __restrict__ partial) {
    const int lane = threadIdx.x & 63;
    const int wave = threadIdx.x >> 6;
    const int rbase = blockIdx.x * RPB;

    __shared__ float spos[RPB][WPB];
    __shared__ float sneg[RPB][WPB];
    __shared__ int   scnt[RPB][WPB];

    v4f xa[4], xb[4];
    v4i ya[4], yb[4];

    // step s: row rbase+s; wave w reads the w-th 4KB quarter of the row.
    // Block-wide footprint per step = one contiguous 16KB row (x) + 16KB (y).
    auto prefetch = [&](v4f (&xv)[4], v4i (&yv)[4], int s) {
        const size_t rowoff = (size_t)(rbase + s) * C_DIM;
        const v4f* __restrict__ x4 = (const v4f*)(x + rowoff);
        const v4i* __restrict__ y4 = (const v4i*)(y + rowoff);
#pragma unroll
        for (int u = 0; u < 4; ++u) {
            const int i = (wave * 4 + u) * 64 + lane;   // contiguous per wave
            xv[u] = __builtin_nontemporal_load(x4 + i);
            yv[u] = __builtin_nontemporal_load(y4 + i);
        }
    };

    float pos, neg; int cnt;
    auto compute = [&](const v4f (&xv)[4], const v4i (&yv)[4]) {
        pos = 0.0f; neg = 0.0f; cnt = 0;
#pragma unroll
        for (int u = 0; u < 4; ++u) {
#pragma unroll
            for (int e = 0; e < 4; ++e) {
                const int   yy = yv[u][e];
                const float xx = xv[u][e];
                const float ex = __expf(yy ? xx : -xx);
                pos += yy ? ex : 0.0f;
                neg += yy ? 0.0f : ex;
                cnt += yy;
            }
        }
    };
    auto flush_row = [&](int s) {
#pragma unroll
        for (int off = 32; off >= 1; off >>= 1) {
            pos += __shfl_down(pos, off, 64);
            neg += __shfl_down(neg, off, 64);
            cnt += __shfl_down(cnt, off, 64);
        }
        if (lane == 0) { spos[s][wave] = pos; sneg[s][wave] = neg; scnt[s][wave] = cnt; }
    };

    // 2-deep pipeline, fully unrolled (static buffer selection)
    prefetch(xa, ya, 0);
    prefetch(xb, yb, 1);
#pragma unroll
    for (int s = 0; s < RPB; ++s) {
        if (s & 1) {
            compute(xb, yb);
            if (s + 2 < RPB) prefetch(xb, yb, s + 2);
        } else {
            compute(xa, ya);
            if (s + 2 < RPB) prefetch(xa, ya, s + 2);
        }
        flush_row(s);
    }

    __syncthreads();
    if (threadIdx.x == 0) {
        float b = 0.0f;
#pragma unroll
        for (int s = 0; s < RPB; ++s) {
            float P = 0.0f, Q = 0.0f; int c = 0;
#pragma unroll
            for (int w = 0; w < WPB; ++w) { P += spos[s][w]; Q += sneg[s][w]; c += scnt[s][w]; }
            b += (P * Q) / ((float)c * (float)(C_DIM - c));
        }
        partial[blockIdx.x] = b;
    }
}

__global__ __launch_bounds__(BLOCK) void pdl_reduce(const float* __restrict__ partial,
                                                    float* __restrict__ out,
                                                    int n_partial, float inv_n) {
    const float4* p4 = (const float4*)partial;
    float s = 0.0f;
    for (int i = threadIdx.x; i < n_partial / 4; i += BLOCK) {
        const float4 v = p4[i];
        s += (v.x + v.y) + (v.z + v.w);
    }
#pragma unroll
    for (int off = 32; off >= 1; off >>= 1) s += __shfl_down(s, off, 64);
    __shared__ float sw[BLOCK / 64];
    const int lane = threadIdx.x & 63;
    const int wave = threadIdx.x >> 6;
    if (lane == 0) sw[wave] = s;
    __syncthreads();
    if (threadIdx.x == 0) {
        float t = 0.0f;
#pragma unroll
        for (int w = 0; w < BLOCK / 64; ++w) t += sw[w];
        out[0] = t * inv_n;
    }
}

extern "C" void kernel_launch(void* const* d_in, const int* in_sizes, int n_in,
                              void* d_out, int out_size, void* d_ws, size_t ws_size,
                              hipStream_t stream) {
    const float* x = (const float*)d_in[0];
    const int*   y = (const int*)d_in[1];
    float* out = (float*)d_out;
    float* partial = (float*)d_ws;  // NBLK floats, fully rewritten each call

    const int n_rows = in_sizes[0] / C_DIM;  // 16384

    pdl_rows<<<NBLK, BLOCK, 0, stream>>>(x, y, partial);
    pdl_reduce<<<1, BLOCK, 0, stream>>>(partial, out, NBLK, 1.0f / (float)n_rows);
}